// Round 3
// baseline (215.220 us; speedup 1.0000x reference)
//
#include <hip/hip_runtime.h>
#include <hip/hip_bf16.h>
#include <stdint.h>

// Problem constants (from reference): B=4096, D=768, N=8192, S=4
#define Bdim 4096
#define Ddim 768
#define Ndim 8192
#define Sdim 4

typedef __attribute__((ext_vector_type(8))) short short8;
typedef __attribute__((ext_vector_type(4))) float floatx4;

// fp32 -> bf16 round-to-nearest-even, as raw ushort
__device__ inline unsigned short f2bf(float f) {
  unsigned u = __builtin_bit_cast(unsigned, f);
  unsigned r = (u + 0x7fffu + ((u >> 16) & 1u)) >> 16;
  return (unsigned short)r;
}
__device__ inline float bf2f(unsigned short s) {
  return __builtin_bit_cast(float, (unsigned)s << 16);
}

// async global->LDS, 16B per lane (global_load_lds_dwordx4)
__device__ inline void async_copy16(const void* g, void* l) {
  __builtin_amdgcn_global_load_lds(
      (__attribute__((address_space(1))) void*)(g),
      (__attribute__((address_space(3))) void*)(l),
      16, 0, 0);
}

// ---------------------------------------------------------------------------
// Kernel 1: fp32 -> bf16 conversion of batch_x and cat; zero stats+counter;
// compute theta[s,b] = exp(batch_x[b] . phi[s]) (one wave per b, blocks 0-1023)
// stats = [s4 (B) | denom (B) | numer (S*B) | counter+pad (256)] floats
// ---------------------------------------------------------------------------
__global__ void convert_kernel(const float* __restrict__ x,
                               const float* __restrict__ cat,
                               const float* __restrict__ phi,
                               unsigned short* __restrict__ xb,
                               unsigned short* __restrict__ catb,
                               float* __restrict__ stats,
                               float* __restrict__ theta) {
  int gid = blockIdx.x * blockDim.x + threadIdx.x;
  int stride = gridDim.x * blockDim.x;
  const int nx4 = (Bdim * Ddim) / 4;
  const int nc4 = (Ndim * Ddim) / 4;
  for (int i = gid; i < nx4; i += stride) {
    float4 v = ((const float4*)x)[i];
    ushort4 o;
    o.x = f2bf(v.x); o.y = f2bf(v.y); o.z = f2bf(v.z); o.w = f2bf(v.w);
    ((ushort4*)xb)[i] = o;
  }
  for (int i = gid; i < nc4; i += stride) {
    float4 v = ((const float4*)cat)[i];
    ushort4 o;
    o.x = f2bf(v.x); o.y = f2bf(v.y); o.z = f2bf(v.z); o.w = f2bf(v.w);
    ((ushort4*)catb)[i] = o;
  }
  if (gid < 6 * Bdim + 256) stats[gid] = 0.0f;

  // theta: one wave per batch row (first 1024 blocks / 4096 waves)
  int gw = gid >> 6;
  int lane = threadIdx.x & 63;
  if (gw < Bdim) {
    const float* xr = x + (size_t)gw * Ddim;
    float a0 = 0.f, a1 = 0.f, a2 = 0.f, a3 = 0.f;
    for (int d = lane; d < Ddim; d += 64) {
      float xv = xr[d];
      a0 = fmaf(xv, phi[d], a0);
      a1 = fmaf(xv, phi[Ddim + d], a1);
      a2 = fmaf(xv, phi[2 * Ddim + d], a2);
      a3 = fmaf(xv, phi[3 * Ddim + d], a3);
    }
#pragma unroll
    for (int off = 32; off > 0; off >>= 1) {
      a0 += __shfl_down(a0, off);
      a1 += __shfl_down(a1, off);
      a2 += __shfl_down(a2, off);
      a3 += __shfl_down(a3, off);
    }
    if (lane == 0) {
      theta[gw] = __expf(a0);
      theta[Bdim + gw] = __expf(a1);
      theta[2 * Bdim + gw] = __expf(a2);
      theta[3 * Bdim + gw] = __expf(a3);
    }
  }
}

// ---------------------------------------------------------------------------
// Kernel 2: bf16 MFMA GEMM  con[n,b] = sum_k cat[n,k]*x[b,k]
// m97 structure: 128x128 tile, BK=32, 4 waves of 64x64, 16x16x32 MFMA,
// global_load_lds width 16. Output stored as bf16 [Ndim, Bdim].
// NOTE (R2 post-mortem): SQ_LDS_BANK_CONFLICT here is exactly 4 cyc per
// ds_read_b128 — structural to b128 wave64 reads (m134: 12 vs 8 cyc ideal),
// NOT avoidable; the R2 XOR swizzle changed nothing on that counter and
// cost 6.5us via scattered global staging sources. Plain layout restored.
// Epilogue accumulates s4[b] += sum_rows con^4 (fused pow4, L3-cheap).
// ---------------------------------------------------------------------------
__global__ __launch_bounds__(256) void gemm_bt_kernel(
    const unsigned short* __restrict__ A,   // cat bf16 [Ndim, Ddim]
    const unsigned short* __restrict__ Bm,  // x   bf16 [Bdim, Ddim]
    unsigned short* __restrict__ C,         // con bf16 [Ndim, Bdim]
    float* __restrict__ s4) {               // [Bdim] p4 column sums
  __shared__ unsigned short As[128 * 32];  // 8 KB
  __shared__ unsigned short Bs[128 * 32];  // 8 KB

  const int tid = threadIdx.x;
  const int wave = tid >> 6;
  const int lane = tid & 63;
  const int quad = lane >> 4;
  const int l16 = lane & 15;
  const int wm = (wave & 1) * 64;
  const int wn = (wave >> 1) * 64;
  const int m0 = blockIdx.x * 128;
  const int n0 = blockIdx.y * 128;

  floatx4 acc[4][4];
#pragma unroll
  for (int i = 0; i < 4; ++i)
#pragma unroll
    for (int j = 0; j < 4; ++j) acc[i][j] = (floatx4){0.f, 0.f, 0.f, 0.f};

  // staging: 512 chunks of 16B per tile; chunk c -> row c>>2, col (c&3)*8.
  // LDS dest offset = chunk*16 -> wave-uniform base + lane*16 (required).
  const int c0 = tid, c1 = tid + 256;
  const int r0 = c0 >> 2, col0 = (c0 & 3) * 8;
  const int r1 = c1 >> 2, col1 = (c1 & 3) * 8;
  const unsigned short* a0 = A + (size_t)(m0 + r0) * Ddim + col0;
  const unsigned short* a1 = A + (size_t)(m0 + r1) * Ddim + col1;
  const unsigned short* b0 = Bm + (size_t)(n0 + r0) * Ddim + col0;
  const unsigned short* b1 = Bm + (size_t)(n0 + r1) * Ddim + col1;

  for (int k0 = 0; k0 < Ddim; k0 += 32) {
    async_copy16(a0 + k0, (char*)As + c0 * 16);
    async_copy16(a1 + k0, (char*)As + c1 * 16);
    async_copy16(b0 + k0, (char*)Bs + c0 * 16);
    async_copy16(b1 + k0, (char*)Bs + c1 * 16);
    __syncthreads();  // drains vmcnt before barrier

    short8 af[4], bf[4];
#pragma unroll
    for (int mi = 0; mi < 4; ++mi)
      af[mi] = *(const short8*)(As + (wm + mi * 16 + l16) * 32 + quad * 8);
#pragma unroll
    for (int ni = 0; ni < 4; ++ni)
      bf[ni] = *(const short8*)(Bs + (wn + ni * 16 + l16) * 32 + quad * 8);
#pragma unroll
    for (int mi = 0; mi < 4; ++mi)
#pragma unroll
      for (int ni = 0; ni < 4; ++ni)
        acc[mi][ni] = __builtin_amdgcn_mfma_f32_16x16x32_bf16(
            af[mi], bf[ni], acc[mi][ni], 0, 0, 0);
    __syncthreads();
  }

  // C/D layout (16x16): col = lane&15, row = quad*4 + reg  [m89-verified]
  float cs4[4] = {0.f, 0.f, 0.f, 0.f};
#pragma unroll
  for (int mi = 0; mi < 4; ++mi)
#pragma unroll
    for (int ni = 0; ni < 4; ++ni) {
      int row = m0 + wm + mi * 16 + quad * 4;
      int col = n0 + wn + ni * 16 + l16;
#pragma unroll
      for (int r = 0; r < 4; ++r) {
        float c = acc[mi][ni][r];
        C[(size_t)(row + r) * Bdim + col] = f2bf(c);
        float c2 = c * c;
        cs4[ni] += c2 * c2;
      }
    }
#pragma unroll
  for (int ni = 0; ni < 4; ++ni) {
    float v = cs4[ni];
    v += __shfl_xor(v, 16);
    v += __shfl_xor(v, 32);
    if (quad == 0) atomicAdd(&s4[n0 + wn + ni * 16 + l16], v);
  }
}

// ---------------------------------------------------------------------------
// Kernel 3: denom[b] += sum exp(con/norm4); numer[s,b] += y-masked sum.
// norm4 >= max|con| so logits are in [-1,1]: no max-subtraction needed.
// Last-block-done: the final block reads denom/numer via agent-scope atomic
// loads (coherent across XCDs) and computes out = sigmoid(sum_s n*theta/d + b).
// grid (Bdim/1024, Ndim/64) = (4, 128) = 512 blocks.
// ---------------------------------------------------------------------------
__global__ void expsum_kernel(const unsigned short* __restrict__ con,
                              const float* __restrict__ s4,
                              const int* __restrict__ y,
                              float* __restrict__ denom,
                              float* __restrict__ numer,
                              const float* __restrict__ theta,
                              const float* __restrict__ bias,
                              int* __restrict__ counter,
                              float* __restrict__ out) {
  int col0 = blockIdx.x * 1024 + threadIdx.x * 4;
  int n0 = blockIdx.y * 64;
  int src = n0 / (Ndim / Sdim);  // 64-row chunk is always within one source

  float4 s = *(const float4*)(s4 + col0);
  float inv0 = 1.0f / fmaxf(sqrtf(sqrtf(s.x)), 1e-12f);
  float inv1 = 1.0f / fmaxf(sqrtf(sqrtf(s.y)), 1e-12f);
  float inv2 = 1.0f / fmaxf(sqrtf(sqrtf(s.z)), 1e-12f);
  float inv3 = 1.0f / fmaxf(sqrtf(sqrtf(s.w)), 1e-12f);

  const unsigned short* p = con + (size_t)n0 * Bdim + col0;
  float d0 = 0.f, d1 = 0.f, d2 = 0.f, d3 = 0.f;
  float m0 = 0.f, m1 = 0.f, m2 = 0.f, m3 = 0.f;
#pragma unroll 8
  for (int i = 0; i < 64; ++i) {
    ushort4 v = *(const ushort4*)(p + (size_t)i * Bdim);
    float yv = (float)y[n0 + i];  // wave-uniform, cached
    float e0 = __expf(bf2f(v.x) * inv0);
    float e1 = __expf(bf2f(v.y) * inv1);
    float e2 = __expf(bf2f(v.z) * inv2);
    float e3 = __expf(bf2f(v.w) * inv3);
    d0 += e0; d1 += e1; d2 += e2; d3 += e3;
    m0 += e0 * yv; m1 += e1 * yv; m2 += e2 * yv; m3 += e3 * yv;
  }
  atomicAdd(&denom[col0 + 0], d0);
  atomicAdd(&denom[col0 + 1], d1);
  atomicAdd(&denom[col0 + 2], d2);
  atomicAdd(&denom[col0 + 3], d3);
  float* np = numer + (size_t)src * Bdim + col0;
  atomicAdd(np + 0, m0);
  atomicAdd(np + 1, m1);
  atomicAdd(np + 2, m2);
  atomicAdd(np + 3, m3);

  // --- last-block finalize ---
  __threadfence();      // release this thread's atomics device-wide
  __syncthreads();      // whole block's atomics now fenced
  __shared__ int is_last;
  if (threadIdx.x == 0) {
    int old = atomicAdd(counter, 1);
    is_last = (old == (int)(gridDim.x * gridDim.y) - 1);
  }
  __syncthreads();
  if (is_last) {
    float bv = bias[0];
    for (int b = threadIdx.x; b < Bdim; b += 256) {
      float den = __hip_atomic_load(&denom[b], __ATOMIC_RELAXED,
                                    __HIP_MEMORY_SCOPE_AGENT);
      float acc = 0.f;
#pragma unroll
      for (int si = 0; si < Sdim; ++si) {
        float nu = __hip_atomic_load(&numer[si * Bdim + b], __ATOMIC_RELAXED,
                                     __HIP_MEMORY_SCOPE_AGENT);
        acc += nu * theta[si * Bdim + b];
      }
      float z = acc / den + bv;
      out[b] = 1.0f / (1.0f + __expf(-z));
    }
  }
}

// ---------------------------------------------------------------------------
// Workspace layout (bytes):
//   catb  : Ndim*Ddim*2        = 12,582,912
//   xb    : Bdim*Ddim*2        =  6,291,456
//   con   : Ndim*Bdim*2        = 67,108,864
//   stats : (6*Bdim+256)*4     =     99,328   (s4 | denom | numer | counter)
//   theta : Sdim*Bdim*4        =     65,536
//   total ≈ 86.1 MB
// ---------------------------------------------------------------------------
extern "C" void kernel_launch(void* const* d_in, const int* in_sizes, int n_in,
                              void* d_out, int out_size, void* d_ws,
                              size_t ws_size, hipStream_t stream) {
  const float* batch_x = (const float*)d_in[0];
  const float* cat = (const float*)d_in[1];
  const int* y = (const int*)d_in[2];
  const float* phi = (const float*)d_in[3];
  const float* bias = (const float*)d_in[4];
  float* out = (float*)d_out;

  char* ws = (char*)d_ws;
  unsigned short* catb = (unsigned short*)ws;
  unsigned short* xb = catb + (size_t)Ndim * Ddim;
  unsigned short* con = xb + (size_t)Bdim * Ddim;
  float* stats = (float*)(con + (size_t)Ndim * Bdim);
  float* s4 = stats;
  float* denom = s4 + Bdim;
  float* numer = denom + Bdim;              // Sdim * Bdim
  int* counter = (int*)(stats + 6 * Bdim);  // zeroed by convert_kernel
  float* theta = stats + 6 * Bdim + 256;    // Sdim * Bdim

  convert_kernel<<<2048, 256, 0, stream>>>(batch_x, cat, phi, xb, catb, stats,
                                           theta);

  dim3 g2(Ndim / 128, Bdim / 128);
  gemm_bt_kernel<<<g2, 256, 0, stream>>>(catb, xb, con, s4);

  dim3 g3(Bdim / 1024, Ndim / 64);
  expsum_kernel<<<g3, 256, 0, stream>>>(con, s4, y, denom, numer, theta, bias,
                                        counter, out);
}

// Round 4
// 204.724 us; speedup vs baseline: 1.0513x; 1.0513x over previous
//
#include <hip/hip_runtime.h>
#include <hip/hip_bf16.h>
#include <stdint.h>

// Problem constants (from reference): B=4096, D=768, N=8192, S=4
#define Bdim 4096
#define Ddim 768
#define Ndim 8192
#define Sdim 4

typedef __attribute__((ext_vector_type(8))) short short8;
typedef __attribute__((ext_vector_type(4))) float floatx4;

// fp32 -> bf16 round-to-nearest-even, as raw ushort
__device__ inline unsigned short f2bf(float f) {
  unsigned u = __builtin_bit_cast(unsigned, f);
  unsigned r = (u + 0x7fffu + ((u >> 16) & 1u)) >> 16;
  return (unsigned short)r;
}
__device__ inline float bf2f(unsigned short s) {
  return __builtin_bit_cast(float, (unsigned)s << 16);
}

// async global->LDS, 16B per lane (global_load_lds_dwordx4)
__device__ inline void async_copy16(const void* g, void* l) {
  __builtin_amdgcn_global_load_lds(
      (__attribute__((address_space(1))) void*)(g),
      (__attribute__((address_space(3))) void*)(l),
      16, 0, 0);
}

// ---------------------------------------------------------------------------
// Kernel 1: fp32 -> bf16 conversion of batch_x and cat; zero the stats region;
// theta[s,b] = exp(batch_x[b] . phi[s])  (one wave per b, first 1024 blocks)
// stats = [s4 (B) | denom (B) | numer (S*B)] floats
// ---------------------------------------------------------------------------
__global__ void convert_kernel(const float* __restrict__ x,
                               const float* __restrict__ cat,
                               const float* __restrict__ phi,
                               unsigned short* __restrict__ xb,
                               unsigned short* __restrict__ catb,
                               float* __restrict__ stats,
                               float* __restrict__ theta) {
  int gid = blockIdx.x * blockDim.x + threadIdx.x;
  int stride = gridDim.x * blockDim.x;
  const int nx4 = (Bdim * Ddim) / 4;
  const int nc4 = (Ndim * Ddim) / 4;
  for (int i = gid; i < nx4; i += stride) {
    float4 v = ((const float4*)x)[i];
    ushort4 o;
    o.x = f2bf(v.x); o.y = f2bf(v.y); o.z = f2bf(v.z); o.w = f2bf(v.w);
    ((ushort4*)xb)[i] = o;
  }
  for (int i = gid; i < nc4; i += stride) {
    float4 v = ((const float4*)cat)[i];
    ushort4 o;
    o.x = f2bf(v.x); o.y = f2bf(v.y); o.z = f2bf(v.z); o.w = f2bf(v.w);
    ((ushort4*)catb)[i] = o;
  }
  if (gid < 6 * Bdim) stats[gid] = 0.0f;

  // theta: one wave per batch row
  int gw = gid >> 6;
  int lane = threadIdx.x & 63;
  if (gw < Bdim) {
    const float* xr = x + (size_t)gw * Ddim;
    float a0 = 0.f, a1 = 0.f, a2 = 0.f, a3 = 0.f;
    for (int d = lane; d < Ddim; d += 64) {
      float xv = xr[d];
      a0 = fmaf(xv, phi[d], a0);
      a1 = fmaf(xv, phi[Ddim + d], a1);
      a2 = fmaf(xv, phi[2 * Ddim + d], a2);
      a3 = fmaf(xv, phi[3 * Ddim + d], a3);
    }
#pragma unroll
    for (int off = 32; off > 0; off >>= 1) {
      a0 += __shfl_down(a0, off);
      a1 += __shfl_down(a1, off);
      a2 += __shfl_down(a2, off);
      a3 += __shfl_down(a3, off);
    }
    if (lane == 0) {
      theta[gw] = __expf(a0);
      theta[Bdim + gw] = __expf(a1);
      theta[2 * Bdim + gw] = __expf(a2);
      theta[3 * Bdim + gw] = __expf(a3);
    }
  }
}

// ---------------------------------------------------------------------------
// Kernel 2: bf16 MFMA GEMM  con[n,b] = sum_k cat[n,k]*x[b,k]
// R4: BK=64 via two lo/hi sub-tiles per operand, each an 8KB 128x32 buffer
// with the SAME internal layout as the BK=32 version -> identical bank
// behavior (SQ_LDS_BANK_CONFLICT is structural 4cyc/ds_read_b128, R1-R3)
// and the global_load_lds lane-contiguity constraint stays satisfied.
// Halves the K-iteration/barrier count: 24 iters x 2 barriers -> 12 x 2.
// XCD-aware tile remap: flat%8 -> each XCD owns 4 consecutive n-tiles
// (xb panel 786KB, L2-resident per XCD; catb streams once).
// Epilogue accumulates s4[b] += sum_rows con^4 (fused pow4).
// ---------------------------------------------------------------------------
__global__ __launch_bounds__(256) void gemm_bt_kernel(
    const unsigned short* __restrict__ A,   // cat bf16 [Ndim, Ddim]
    const unsigned short* __restrict__ Bm,  // x   bf16 [Bdim, Ddim]
    unsigned short* __restrict__ C,         // con bf16 [Ndim, Bdim]
    float* __restrict__ s4) {               // [Bdim] p4 column sums
  __shared__ unsigned short As[2][128 * 32];  // lo/hi, 8 KB each
  __shared__ unsigned short Bs[2][128 * 32];

  const int tid = threadIdx.x;
  const int wave = tid >> 6;
  const int lane = tid & 63;
  const int quad = lane >> 4;
  const int l16 = lane & 15;
  const int wm = (wave & 1) * 64;
  const int wn = (wave >> 1) * 64;

  // XCD swizzle: grid is (64, 32) x-major; xcd = flat%8 heuristic.
  // Each XCD gets n-tiles [xcd*4, xcd*4+4) over all 64 m-tiles.
  const int f = blockIdx.x + 64 * blockIdx.y;
  const int xcd = f & 7;
  const int i = f >> 3;                 // 0..255
  const int m0 = (i & 63) * 128;
  const int n0 = (xcd * 4 + (i >> 6)) * 128;

  floatx4 acc[4][4];
#pragma unroll
  for (int a = 0; a < 4; ++a)
#pragma unroll
    for (int b = 0; b < 4; ++b) acc[a][b] = (floatx4){0.f, 0.f, 0.f, 0.f};

  // staging: per 8KB sub-tile, 512 chunks of 16B; chunk c -> row c>>2,
  // col (c&3)*8. LDS dest offset = chunk*16 (wave-uniform base + lane*16).
  const int c0 = tid, c1 = tid + 256;
  const int r0 = c0 >> 2, col0 = (c0 & 3) * 8;
  const int r1 = c1 >> 2, col1 = (c1 & 3) * 8;
  const unsigned short* a0 = A + (size_t)(m0 + r0) * Ddim + col0;
  const unsigned short* a1 = A + (size_t)(m0 + r1) * Ddim + col1;
  const unsigned short* b0 = Bm + (size_t)(n0 + r0) * Ddim + col0;
  const unsigned short* b1 = Bm + (size_t)(n0 + r1) * Ddim + col1;

  for (int k0 = 0; k0 < Ddim; k0 += 64) {
    async_copy16(a0 + k0, (char*)As[0] + c0 * 16);
    async_copy16(a1 + k0, (char*)As[0] + c1 * 16);
    async_copy16(a0 + k0 + 32, (char*)As[1] + c0 * 16);
    async_copy16(a1 + k0 + 32, (char*)As[1] + c1 * 16);
    async_copy16(b0 + k0, (char*)Bs[0] + c0 * 16);
    async_copy16(b1 + k0, (char*)Bs[0] + c1 * 16);
    async_copy16(b0 + k0 + 32, (char*)Bs[1] + c0 * 16);
    async_copy16(b1 + k0 + 32, (char*)Bs[1] + c1 * 16);
    __syncthreads();  // drains vmcnt before barrier

#pragma unroll
    for (int h = 0; h < 2; ++h) {
      short8 af[4], bf[4];
#pragma unroll
      for (int mi = 0; mi < 4; ++mi)
        af[mi] = *(const short8*)(As[h] + (wm + mi * 16 + l16) * 32 + quad * 8);
#pragma unroll
      for (int ni = 0; ni < 4; ++ni)
        bf[ni] = *(const short8*)(Bs[h] + (wn + ni * 16 + l16) * 32 + quad * 8);
#pragma unroll
      for (int mi = 0; mi < 4; ++mi)
#pragma unroll
        for (int ni = 0; ni < 4; ++ni)
          acc[mi][ni] = __builtin_amdgcn_mfma_f32_16x16x32_bf16(
              af[mi], bf[ni], acc[mi][ni], 0, 0, 0);
    }
    __syncthreads();
  }

  // C/D layout (16x16): col = lane&15, row = quad*4 + reg  [m89-verified]
  float cs4[4] = {0.f, 0.f, 0.f, 0.f};
#pragma unroll
  for (int mi = 0; mi < 4; ++mi)
#pragma unroll
    for (int ni = 0; ni < 4; ++ni) {
      int row = m0 + wm + mi * 16 + quad * 4;
      int col = n0 + wn + ni * 16 + l16;
#pragma unroll
      for (int r = 0; r < 4; ++r) {
        float c = acc[mi][ni][r];
        C[(size_t)(row + r) * Bdim + col] = f2bf(c);
        float c2 = c * c;
        cs4[ni] += c2 * c2;
      }
    }
#pragma unroll
  for (int ni = 0; ni < 4; ++ni) {
    float v = cs4[ni];
    v += __shfl_xor(v, 16);
    v += __shfl_xor(v, 32);
    if (quad == 0) atomicAdd(&s4[n0 + wn + ni * 16 + l16], v);
  }
}

// ---------------------------------------------------------------------------
// Kernel 3: denom[b] += sum exp(con/norm4); numer[s,b] += y-masked sum.
// norm4 >= max|con| so logits are in [-1,1]: no max-subtraction needed.
// NO in-kernel fence/finalize (R3: per-block __threadfence = device-scope
// L2 writeback, cost ~25us across 512 blocks; cross-dispatch stream
// ordering is the cheap coherence path on CDNA4).
// ---------------------------------------------------------------------------
__global__ void expsum_kernel(const unsigned short* __restrict__ con,
                              const float* __restrict__ s4,
                              const int* __restrict__ y,
                              float* __restrict__ denom,
                              float* __restrict__ numer) {
  int col0 = blockIdx.x * 1024 + threadIdx.x * 4;
  int n0 = blockIdx.y * 64;
  int src = n0 / (Ndim / Sdim);  // 64-row chunk is always within one source

  float4 s = *(const float4*)(s4 + col0);
  float inv0 = 1.0f / fmaxf(sqrtf(sqrtf(s.x)), 1e-12f);
  float inv1 = 1.0f / fmaxf(sqrtf(sqrtf(s.y)), 1e-12f);
  float inv2 = 1.0f / fmaxf(sqrtf(sqrtf(s.z)), 1e-12f);
  float inv3 = 1.0f / fmaxf(sqrtf(sqrtf(s.w)), 1e-12f);

  const unsigned short* p = con + (size_t)n0 * Bdim + col0;
  float d0 = 0.f, d1 = 0.f, d2 = 0.f, d3 = 0.f;
  float m0 = 0.f, m1 = 0.f, m2 = 0.f, m3 = 0.f;
#pragma unroll 8
  for (int i = 0; i < 64; ++i) {
    ushort4 v = *(const ushort4*)(p + (size_t)i * Bdim);
    float yv = (float)y[n0 + i];  // wave-uniform, cached
    float e0 = __expf(bf2f(v.x) * inv0);
    float e1 = __expf(bf2f(v.y) * inv1);
    float e2 = __expf(bf2f(v.z) * inv2);
    float e3 = __expf(bf2f(v.w) * inv3);
    d0 += e0; d1 += e1; d2 += e2; d3 += e3;
    m0 += e0 * yv; m1 += e1 * yv; m2 += e2 * yv; m3 += e3 * yv;
  }
  atomicAdd(&denom[col0 + 0], d0);
  atomicAdd(&denom[col0 + 1], d1);
  atomicAdd(&denom[col0 + 2], d2);
  atomicAdd(&denom[col0 + 3], d3);
  float* np = numer + (size_t)src * Bdim + col0;
  atomicAdd(np + 0, m0);
  atomicAdd(np + 1, m1);
  atomicAdd(np + 2, m2);
  atomicAdd(np + 3, m3);
}

// ---------------------------------------------------------------------------
// Kernel 4 (tiny): out[b] = sigmoid(sum_s numer[s,b]*theta[s,b]/denom[b]+bias)
// theta precomputed in convert_kernel. 16 blocks, fully coalesced.
// ---------------------------------------------------------------------------
__global__ void finalize_kernel(const float* __restrict__ denom,
                                const float* __restrict__ numer,
                                const float* __restrict__ theta,
                                const float* __restrict__ bias,
                                float* __restrict__ out) {
  int b = blockIdx.x * 256 + threadIdx.x;
  float acc = 0.f;
#pragma unroll
  for (int si = 0; si < Sdim; ++si)
    acc += numer[si * Bdim + b] * theta[si * Bdim + b];
  float z = acc / denom[b] + bias[0];
  out[b] = 1.0f / (1.0f + __expf(-z));
}

// ---------------------------------------------------------------------------
// Workspace layout (bytes):
//   catb  : Ndim*Ddim*2   = 12,582,912
//   xb    : Bdim*Ddim*2   =  6,291,456
//   con   : Ndim*Bdim*2   = 67,108,864
//   stats : 6*Bdim*4      =     98,304   (s4 | denom | numer)
//   theta : Sdim*Bdim*4   =     65,536
//   total ≈ 86.1 MB
// ---------------------------------------------------------------------------
extern "C" void kernel_launch(void* const* d_in, const int* in_sizes, int n_in,
                              void* d_out, int out_size, void* d_ws,
                              size_t ws_size, hipStream_t stream) {
  const float* batch_x = (const float*)d_in[0];
  const float* cat = (const float*)d_in[1];
  const int* y = (const int*)d_in[2];
  const float* phi = (const float*)d_in[3];
  const float* bias = (const float*)d_in[4];
  float* out = (float*)d_out;

  char* ws = (char*)d_ws;
  unsigned short* catb = (unsigned short*)ws;
  unsigned short* xb = catb + (size_t)Ndim * Ddim;
  unsigned short* con = xb + (size_t)Bdim * Ddim;
  float* stats = (float*)(con + (size_t)Ndim * Bdim);
  float* s4 = stats;
  float* denom = s4 + Bdim;
  float* numer = denom + Bdim;           // Sdim * Bdim
  float* theta = stats + 6 * Bdim;       // Sdim * Bdim

  convert_kernel<<<2048, 256, 0, stream>>>(batch_x, cat, phi, xb, catb, stats,
                                           theta);

  dim3 g2(Ndim / 128, Bdim / 128);
  gemm_bt_kernel<<<g2, 256, 0, stream>>>(catb, xb, con, s4);

  dim3 g3(Bdim / 1024, Ndim / 64);
  expsum_kernel<<<g3, 256, 0, stream>>>(con, s4, y, denom, numer);

  finalize_kernel<<<Bdim / 256, 256, 0, stream>>>(denom, numer, theta, bias,
                                                  out);
}

// Round 6
// 190.769 us; speedup vs baseline: 1.1282x; 1.0732x over previous
//
#include <hip/hip_runtime.h>
#include <hip/hip_bf16.h>
#include <stdint.h>

// Problem constants (from reference): B=4096, D=768, N=8192, S=4
#define Bdim 4096
#define Ddim 768
#define Ndim 8192
#define Sdim 4

typedef __attribute__((ext_vector_type(8))) short short8;
typedef __attribute__((ext_vector_type(4))) float floatx4;

// fp32 -> bf16 round-to-nearest-even, as raw ushort
__device__ inline unsigned short f2bf(float f) {
  unsigned u = __builtin_bit_cast(unsigned, f);
  unsigned r = (u + 0x7fffu + ((u >> 16) & 1u)) >> 16;
  return (unsigned short)r;
}
__device__ inline float bf2f(unsigned short s) {
  return __builtin_bit_cast(float, (unsigned)s << 16);
}

// async global->LDS, 16B per lane (global_load_lds_dwordx4)
__device__ inline void async_copy16(const void* g, void* l) {
  __builtin_amdgcn_global_load_lds(
      (__attribute__((address_space(1))) void*)(g),
      (__attribute__((address_space(3))) void*)(l),
      16, 0, 0);
}

// ---------------------------------------------------------------------------
// Kernel 1: fp32 -> bf16 conversion of batch_x and cat; zero the stats region;
// theta[s,b] = exp(batch_x[b] . phi[s])  (one wave per b, first 1024 blocks)
// stats = [s4 (B) | denom (B) | numer (S*B)] floats
// ---------------------------------------------------------------------------
__global__ void convert_kernel(const float* __restrict__ x,
                               const float* __restrict__ cat,
                               const float* __restrict__ phi,
                               unsigned short* __restrict__ xb,
                               unsigned short* __restrict__ catb,
                               float* __restrict__ stats,
                               float* __restrict__ theta) {
  int gid = blockIdx.x * blockDim.x + threadIdx.x;
  int stride = gridDim.x * blockDim.x;
  const int nx4 = (Bdim * Ddim) / 4;
  const int nc4 = (Ndim * Ddim) / 4;
  for (int i = gid; i < nx4; i += stride) {
    float4 v = ((const float4*)x)[i];
    ushort4 o;
    o.x = f2bf(v.x); o.y = f2bf(v.y); o.z = f2bf(v.z); o.w = f2bf(v.w);
    ((ushort4*)xb)[i] = o;
  }
  for (int i = gid; i < nc4; i += stride) {
    float4 v = ((const float4*)cat)[i];
    ushort4 o;
    o.x = f2bf(v.x); o.y = f2bf(v.y); o.z = f2bf(v.z); o.w = f2bf(v.w);
    ((ushort4*)catb)[i] = o;
  }
  if (gid < 6 * Bdim) stats[gid] = 0.0f;

  // theta: one wave per batch row
  int gw = gid >> 6;
  int lane = threadIdx.x & 63;
  if (gw < Bdim) {
    const float* xr = x + (size_t)gw * Ddim;
    float a0 = 0.f, a1 = 0.f, a2 = 0.f, a3 = 0.f;
    for (int d = lane; d < Ddim; d += 64) {
      float xv = xr[d];
      a0 = fmaf(xv, phi[d], a0);
      a1 = fmaf(xv, phi[Ddim + d], a1);
      a2 = fmaf(xv, phi[2 * Ddim + d], a2);
      a3 = fmaf(xv, phi[3 * Ddim + d], a3);
    }
#pragma unroll
    for (int off = 32; off > 0; off >>= 1) {
      a0 += __shfl_down(a0, off);
      a1 += __shfl_down(a1, off);
      a2 += __shfl_down(a2, off);
      a3 += __shfl_down(a3, off);
    }
    if (lane == 0) {
      theta[gw] = __expf(a0);
      theta[Bdim + gw] = __expf(a1);
      theta[2 * Bdim + gw] = __expf(a2);
      theta[3 * Bdim + gw] = __expf(a3);
    }
  }
}

// ---------------------------------------------------------------------------
// Kernel 2: bf16 MFMA GEMM  con[n,b] = sum_k cat[n,k]*x[b,k]
// R3-EXACT core (80.8us measured): 128x128 tile, BK=32, 4 waves of 64x64,
// 16x16x32 MFMA, global_load_lds w=16, natural x-major grid (64 consecutive
// blocks share one B-panel -> L2 locality; R4's XCD remap thrashed L2,
// FETCH 42->200MB — do not remap block->tile on an unverified XCD model).
// SQ_LDS_BANK_CONFLICT here is structural (4cyc/ds_read_b128, R1-R3 const).
// Epilogue accumulates s4[b] += sum_rows con^4 (fused pow4, saves a pass).
// ---------------------------------------------------------------------------
__global__ __launch_bounds__(256) void gemm_bt_kernel(
    const unsigned short* __restrict__ A,   // cat bf16 [Ndim, Ddim]
    const unsigned short* __restrict__ Bm,  // x   bf16 [Bdim, Ddim]
    unsigned short* __restrict__ C,         // con bf16 [Ndim, Bdim]
    float* __restrict__ s4) {               // [Bdim] p4 column sums
  __shared__ unsigned short As[128 * 32];  // 8 KB
  __shared__ unsigned short Bs[128 * 32];  // 8 KB

  const int tid = threadIdx.x;
  const int wave = tid >> 6;
  const int lane = tid & 63;
  const int quad = lane >> 4;
  const int l16 = lane & 15;
  const int wm = (wave & 1) * 64;
  const int wn = (wave >> 1) * 64;
  const int m0 = blockIdx.x * 128;
  const int n0 = blockIdx.y * 128;

  floatx4 acc[4][4];
#pragma unroll
  for (int i = 0; i < 4; ++i)
#pragma unroll
    for (int j = 0; j < 4; ++j) acc[i][j] = (floatx4){0.f, 0.f, 0.f, 0.f};

  // staging: 512 chunks of 16B per tile; chunk c -> row c>>2, col (c&3)*8.
  // LDS dest offset = chunk*16 -> wave-uniform base + lane*16 (required).
  const int c0 = tid, c1 = tid + 256;
  const int r0 = c0 >> 2, col0 = (c0 & 3) * 8;
  const int r1 = c1 >> 2, col1 = (c1 & 3) * 8;
  const unsigned short* a0 = A + (size_t)(m0 + r0) * Ddim + col0;
  const unsigned short* a1 = A + (size_t)(m0 + r1) * Ddim + col1;
  const unsigned short* b0 = Bm + (size_t)(n0 + r0) * Ddim + col0;
  const unsigned short* b1 = Bm + (size_t)(n0 + r1) * Ddim + col1;

  for (int k0 = 0; k0 < Ddim; k0 += 32) {
    async_copy16(a0 + k0, (char*)As + c0 * 16);
    async_copy16(a1 + k0, (char*)As + c1 * 16);
    async_copy16(b0 + k0, (char*)Bs + c0 * 16);
    async_copy16(b1 + k0, (char*)Bs + c1 * 16);
    __syncthreads();  // drains vmcnt before barrier

    short8 af[4], bf[4];
#pragma unroll
    for (int mi = 0; mi < 4; ++mi)
      af[mi] = *(const short8*)(As + (wm + mi * 16 + l16) * 32 + quad * 8);
#pragma unroll
    for (int ni = 0; ni < 4; ++ni)
      bf[ni] = *(const short8*)(Bs + (wn + ni * 16 + l16) * 32 + quad * 8);
#pragma unroll
    for (int mi = 0; mi < 4; ++mi)
#pragma unroll
      for (int ni = 0; ni < 4; ++ni)
        acc[mi][ni] = __builtin_amdgcn_mfma_f32_16x16x32_bf16(
            af[mi], bf[ni], acc[mi][ni], 0, 0, 0);
    __syncthreads();
  }

  // C/D layout (16x16): col = lane&15, row = quad*4 + reg  [m89-verified]
  float cs4[4] = {0.f, 0.f, 0.f, 0.f};
#pragma unroll
  for (int mi = 0; mi < 4; ++mi)
#pragma unroll
    for (int ni = 0; ni < 4; ++ni) {
      int row = m0 + wm + mi * 16 + quad * 4;
      int col = n0 + wn + ni * 16 + l16;
#pragma unroll
      for (int r = 0; r < 4; ++r) {
        float c = acc[mi][ni][r];
        C[(size_t)(row + r) * Bdim + col] = f2bf(c);
        float c2 = c * c;
        cs4[ni] += c2 * c2;
      }
    }
#pragma unroll
  for (int ni = 0; ni < 4; ++ni) {
    float v = cs4[ni];
    v += __shfl_xor(v, 16);
    v += __shfl_xor(v, 32);
    if (quad == 0) atomicAdd(&s4[n0 + wn + ni * 16 + l16], v);
  }
}

// ---------------------------------------------------------------------------
// Kernel 3: denom[b] += sum exp(con/norm4); numer[s,b] += y-masked sum.
// norm4 >= max|con| so logits are in [-1,1]: no max-subtraction needed.
// Thread owns 4 consecutive columns (ushort4 loads, 512B/wave coalesced).
// No in-kernel fence/finalize (R3: 512 device fences cost ~25us; R5:
// cooperative sync unlaunchable) — stream ordering is the coherence path.
// ---------------------------------------------------------------------------
__global__ void expsum_kernel(const unsigned short* __restrict__ con,
                              const float* __restrict__ s4,
                              const int* __restrict__ y,
                              float* __restrict__ denom,
                              float* __restrict__ numer) {
  int col0 = blockIdx.x * 1024 + threadIdx.x * 4;
  int n0 = blockIdx.y * 64;
  int src = n0 / (Ndim / Sdim);  // 64-row chunk is always within one source

  float4 s = *(const float4*)(s4 + col0);
  float inv0 = 1.0f / fmaxf(sqrtf(sqrtf(s.x)), 1e-12f);
  float inv1 = 1.0f / fmaxf(sqrtf(sqrtf(s.y)), 1e-12f);
  float inv2 = 1.0f / fmaxf(sqrtf(sqrtf(s.z)), 1e-12f);
  float inv3 = 1.0f / fmaxf(sqrtf(sqrtf(s.w)), 1e-12f);

  const unsigned short* p = con + (size_t)n0 * Bdim + col0;
  float d0 = 0.f, d1 = 0.f, d2 = 0.f, d3 = 0.f;
  float m0 = 0.f, m1 = 0.f, m2 = 0.f, m3 = 0.f;
#pragma unroll 8
  for (int i = 0; i < 64; ++i) {
    ushort4 v = *(const ushort4*)(p + (size_t)i * Bdim);
    float yv = (float)y[n0 + i];  // wave-uniform, cached
    float e0 = __expf(bf2f(v.x) * inv0);
    float e1 = __expf(bf2f(v.y) * inv1);
    float e2 = __expf(bf2f(v.z) * inv2);
    float e3 = __expf(bf2f(v.w) * inv3);
    d0 += e0; d1 += e1; d2 += e2; d3 += e3;
    m0 += e0 * yv; m1 += e1 * yv; m2 += e2 * yv; m3 += e3 * yv;
  }
  atomicAdd(&denom[col0 + 0], d0);
  atomicAdd(&denom[col0 + 1], d1);
  atomicAdd(&denom[col0 + 2], d2);
  atomicAdd(&denom[col0 + 3], d3);
  float* np = numer + (size_t)src * Bdim + col0;
  atomicAdd(np + 0, m0);
  atomicAdd(np + 1, m1);
  atomicAdd(np + 2, m2);
  atomicAdd(np + 3, m3);
}

// ---------------------------------------------------------------------------
// Kernel 4 (tiny): out[b] = sigmoid(sum_s numer[s,b]*theta[s,b]/denom[b]+bias)
// ---------------------------------------------------------------------------
__global__ void finalize_kernel(const float* __restrict__ denom,
                                const float* __restrict__ numer,
                                const float* __restrict__ theta,
                                const float* __restrict__ bias,
                                float* __restrict__ out) {
  int b = blockIdx.x * 256 + threadIdx.x;
  float acc = 0.f;
#pragma unroll
  for (int si = 0; si < Sdim; ++si)
    acc += numer[si * Bdim + b] * theta[si * Bdim + b];
  float z = acc / denom[b] + bias[0];
  out[b] = 1.0f / (1.0f + __expf(-z));
}

// ---------------------------------------------------------------------------
// Workspace layout (bytes):
//   catb  : Ndim*Ddim*2   = 12,582,912
//   xb    : Bdim*Ddim*2   =  6,291,456
//   con   : Ndim*Bdim*2   = 67,108,864
//   stats : 6*Bdim*4      =     98,304   (s4 | denom | numer)
//   theta : Sdim*Bdim*4   =     65,536
//   total ≈ 86.1 MB
// ---------------------------------------------------------------------------
extern "C" void kernel_launch(void* const* d_in, const int* in_sizes, int n_in,
                              void* d_out, int out_size, void* d_ws,
                              size_t ws_size, hipStream_t stream) {
  const float* batch_x = (const float*)d_in[0];
  const float* cat = (const float*)d_in[1];
  const int* y = (const int*)d_in[2];
  const float* phi = (const float*)d_in[3];
  const float* bias = (const float*)d_in[4];
  float* out = (float*)d_out;

  char* ws = (char*)d_ws;
  unsigned short* catb = (unsigned short*)ws;
  unsigned short* xb = catb + (size_t)Ndim * Ddim;
  unsigned short* con = xb + (size_t)Bdim * Ddim;
  float* stats = (float*)(con + (size_t)Ndim * Bdim);
  float* s4 = stats;
  float* denom = s4 + Bdim;
  float* numer = denom + Bdim;        // Sdim * Bdim
  float* theta = stats + 6 * Bdim;    // Sdim * Bdim

  convert_kernel<<<2048, 256, 0, stream>>>(batch_x, cat, phi, xb, catb, stats,
                                           theta);

  dim3 g2(Ndim / 128, Bdim / 128);
  gemm_bt_kernel<<<g2, 256, 0, stream>>>(catb, xb, con, s4);

  dim3 g3(Bdim / 1024, Ndim / 64);
  expsum_kernel<<<g3, 256, 0, stream>>>(con, s4, y, denom, numer);

  finalize_kernel<<<Bdim / 256, 256, 0, stream>>>(denom, numer, theta, bias,
                                                  out);
}

// Round 7
// 181.111 us; speedup vs baseline: 1.1883x; 1.0533x over previous
//
#include <hip/hip_runtime.h>
#include <hip/hip_bf16.h>
#include <stdint.h>

// Problem constants (from reference): B=4096, D=768, N=8192, S=4
#define Bdim 4096
#define Ddim 768
#define Ndim 8192
#define Sdim 4

typedef __attribute__((ext_vector_type(4))) float floatx4;

// fp32 -> bf16 round-to-nearest-even, as raw ushort
__device__ inline unsigned short f2bf(float f) {
  unsigned u = __builtin_bit_cast(unsigned, f);
  unsigned r = (u + 0x7fffu + ((u >> 16) & 1u)) >> 16;
  return (unsigned short)r;
}
__device__ inline float bf2f(unsigned short s) {
  return __builtin_bit_cast(float, (unsigned)s << 16);
}

// pack float4 -> 4x fp8 e4m3 (OCP on gfx950), HW RNE
__device__ inline int pack_fp8x4(float4 v) {
  int r = __builtin_amdgcn_cvt_pk_fp8_f32(v.x, v.y, 0, 0);      // low word
  r = __builtin_amdgcn_cvt_pk_fp8_f32(v.z, v.w, r, 1);          // high word
  return r;
}

// async global->LDS, 16B per lane (global_load_lds_dwordx4)
__device__ inline void async_copy16(const void* g, void* l) {
  __builtin_amdgcn_global_load_lds(
      (__attribute__((address_space(1))) void*)(g),
      (__attribute__((address_space(3))) void*)(l),
      16, 0, 0);
}

// ---------------------------------------------------------------------------
// Kernel 1: fp32 -> fp8 e4m3 quantization of batch_x and cat (inputs ~N(0,1),
// |x| << 448 so no saturation); zero the stats region; theta[s,b] =
// exp(batch_x[b] . phi[s]) in fp32 (one wave per b, first 1024 blocks).
// stats = [s4 (B) | denom (B) | numer (S*B)] floats
// ---------------------------------------------------------------------------
__global__ void convert_kernel(const float* __restrict__ x,
                               const float* __restrict__ cat,
                               const float* __restrict__ phi,
                               unsigned char* __restrict__ xq,
                               unsigned char* __restrict__ catq,
                               float* __restrict__ stats,
                               float* __restrict__ theta) {
  int gid = blockIdx.x * blockDim.x + threadIdx.x;
  int stride = gridDim.x * blockDim.x;
  const int nx4 = (Bdim * Ddim) / 4;
  const int nc4 = (Ndim * Ddim) / 4;
  for (int i = gid; i < nx4; i += stride)
    ((int*)xq)[i] = pack_fp8x4(((const float4*)x)[i]);
  for (int i = gid; i < nc4; i += stride)
    ((int*)catq)[i] = pack_fp8x4(((const float4*)cat)[i]);
  if (gid < 6 * Bdim) stats[gid] = 0.0f;

  // theta: one wave per batch row (fp32 — exact path, output-critical)
  int gw = gid >> 6;
  int lane = threadIdx.x & 63;
  if (gw < Bdim) {
    const float* xr = x + (size_t)gw * Ddim;
    float a0 = 0.f, a1 = 0.f, a2 = 0.f, a3 = 0.f;
    for (int d = lane; d < Ddim; d += 64) {
      float xv = xr[d];
      a0 = fmaf(xv, phi[d], a0);
      a1 = fmaf(xv, phi[Ddim + d], a1);
      a2 = fmaf(xv, phi[2 * Ddim + d], a2);
      a3 = fmaf(xv, phi[3 * Ddim + d], a3);
    }
#pragma unroll
    for (int off = 32; off > 0; off >>= 1) {
      a0 += __shfl_down(a0, off);
      a1 += __shfl_down(a1, off);
      a2 += __shfl_down(a2, off);
      a3 += __shfl_down(a3, off);
    }
    if (lane == 0) {
      theta[gw] = __expf(a0);
      theta[Bdim + gw] = __expf(a1);
      theta[2 * Bdim + gw] = __expf(a2);
      theta[3 * Bdim + gw] = __expf(a3);
    }
  }
}

// ---------------------------------------------------------------------------
// Kernel 2: fp8 e4m3 MFMA GEMM  con[n,b] = sum_k cat[n,k]*x[b,k]
// m145-style port of the R3/R6 structure (79us bf16 measured): 128x128 tile,
// 16x16x32_fp8_fp8 MFMA (A/B = 8 fp8 per lane, k = quad*8+j — same geometry
// as the bf16 16x16x32 fragment), global_load_lds w=16.
// BK=64 via lo/hi 4KB sub-buffers: half the staging bytes AND half the
// K-iterations/barrier drains (24 -> 12) at the SAME 16KB LDS (occupancy
// unchanged) — the R4 lo/hi trick, now without the XCD-remap confound.
// Natural x-major grid (R4 lesson: no XCD remapping).
// Epilogue: bf16 C-write + fused pow4 (acc fp32, unchanged from R6).
// ---------------------------------------------------------------------------
__global__ __launch_bounds__(256) void gemm_bt_kernel(
    const unsigned char* __restrict__ A,    // cat fp8 [Ndim, Ddim]
    const unsigned char* __restrict__ Bm,   // x   fp8 [Bdim, Ddim]
    unsigned short* __restrict__ C,         // con bf16 [Ndim, Bdim]
    float* __restrict__ s4) {               // [Bdim] p4 column sums
  __shared__ unsigned char As[2][128 * 32];  // lo/hi 4 KB each
  __shared__ unsigned char Bs[2][128 * 32];

  const int tid = threadIdx.x;
  const int wave = tid >> 6;
  const int lane = tid & 63;
  const int quad = lane >> 4;
  const int l16 = lane & 15;
  const int wm = (wave & 1) * 64;
  const int wn = (wave >> 1) * 64;
  const int m0 = blockIdx.x * 128;
  const int n0 = blockIdx.y * 128;

  floatx4 acc[4][4];
#pragma unroll
  for (int i = 0; i < 4; ++i)
#pragma unroll
    for (int j = 0; j < 4; ++j) acc[i][j] = (floatx4){0.f, 0.f, 0.f, 0.f};

  // staging: per 4KB sub-buffer 256 chunks of 16B; chunk c -> row c>>1,
  // byte-col (c&1)*16. One chunk per thread per sub-buffer.
  // LDS dest = c*16 (wave-uniform base + lane*16, as required).
  const int c = tid;
  const int r = c >> 1, colb = (c & 1) * 16;
  const unsigned char* a_src = A + (size_t)(m0 + r) * Ddim + colb;
  const unsigned char* b_src = Bm + (size_t)(n0 + r) * Ddim + colb;

  for (int k0 = 0; k0 < Ddim; k0 += 64) {
    async_copy16(a_src + k0, As[0] + c * 16);
    async_copy16(a_src + k0 + 32, As[1] + c * 16);
    async_copy16(b_src + k0, Bs[0] + c * 16);
    async_copy16(b_src + k0 + 32, Bs[1] + c * 16);
    __syncthreads();  // drains vmcnt before barrier

#pragma unroll
    for (int h = 0; h < 2; ++h) {
      long af[4], bf[4];
#pragma unroll
      for (int mi = 0; mi < 4; ++mi)
        af[mi] = *(const long*)(As[h] + (wm + mi * 16 + l16) * 32 + quad * 8);
#pragma unroll
      for (int ni = 0; ni < 4; ++ni)
        bf[ni] = *(const long*)(Bs[h] + (wn + ni * 16 + l16) * 32 + quad * 8);
#pragma unroll
      for (int mi = 0; mi < 4; ++mi)
#pragma unroll
        for (int ni = 0; ni < 4; ++ni)
          acc[mi][ni] = __builtin_amdgcn_mfma_f32_16x16x32_fp8_fp8(
              af[mi], bf[ni], acc[mi][ni], 0, 0, 0);
    }
    __syncthreads();
  }

  // C/D layout (16x16): col = lane&15, row = quad*4 + reg  [m89-verified,
  // dtype-independent]. Fused pow4 epilogue unchanged.
  float cs4[4] = {0.f, 0.f, 0.f, 0.f};
#pragma unroll
  for (int mi = 0; mi < 4; ++mi)
#pragma unroll
    for (int ni = 0; ni < 4; ++ni) {
      int row = m0 + wm + mi * 16 + quad * 4;
      int col = n0 + wn + ni * 16 + l16;
#pragma unroll
      for (int rr = 0; rr < 4; ++rr) {
        float cv = acc[mi][ni][rr];
        C[(size_t)(row + rr) * Bdim + col] = f2bf(cv);
        float c2 = cv * cv;
        cs4[ni] += c2 * c2;
      }
    }
#pragma unroll
  for (int ni = 0; ni < 4; ++ni) {
    float v = cs4[ni];
    v += __shfl_xor(v, 16);
    v += __shfl_xor(v, 32);
    if (quad == 0) atomicAdd(&s4[n0 + wn + ni * 16 + l16], v);
  }
}

// ---------------------------------------------------------------------------
// Kernel 3: denom[b] += sum exp(con/norm4); numer[s,b] += y-masked sum.
// norm4 >= max|con| so logits are in [-1,1]: no max-subtraction needed.
// Thread owns 4 consecutive columns (ushort4 loads, 512B/wave coalesced).
// Stream ordering (not fences) is the cross-kernel coherence path (R3/R5).
// ---------------------------------------------------------------------------
__global__ void expsum_kernel(const unsigned short* __restrict__ con,
                              const float* __restrict__ s4,
                              const int* __restrict__ y,
                              float* __restrict__ denom,
                              float* __restrict__ numer) {
  int col0 = blockIdx.x * 1024 + threadIdx.x * 4;
  int n0 = blockIdx.y * 64;
  int src = n0 / (Ndim / Sdim);  // 64-row chunk is always within one source

  float4 s = *(const float4*)(s4 + col0);
  float inv0 = 1.0f / fmaxf(sqrtf(sqrtf(s.x)), 1e-12f);
  float inv1 = 1.0f / fmaxf(sqrtf(sqrtf(s.y)), 1e-12f);
  float inv2 = 1.0f / fmaxf(sqrtf(sqrtf(s.z)), 1e-12f);
  float inv3 = 1.0f / fmaxf(sqrtf(sqrtf(s.w)), 1e-12f);

  const unsigned short* p = con + (size_t)n0 * Bdim + col0;
  float d0 = 0.f, d1 = 0.f, d2 = 0.f, d3 = 0.f;
  float m0 = 0.f, m1 = 0.f, m2 = 0.f, m3 = 0.f;
#pragma unroll 8
  for (int i = 0; i < 64; ++i) {
    ushort4 v = *(const ushort4*)(p + (size_t)i * Bdim);
    float yv = (float)y[n0 + i];  // wave-uniform, cached
    float e0 = __expf(bf2f(v.x) * inv0);
    float e1 = __expf(bf2f(v.y) * inv1);
    float e2 = __expf(bf2f(v.z) * inv2);
    float e3 = __expf(bf2f(v.w) * inv3);
    d0 += e0; d1 += e1; d2 += e2; d3 += e3;
    m0 += e0 * yv; m1 += e1 * yv; m2 += e2 * yv; m3 += e3 * yv;
  }
  atomicAdd(&denom[col0 + 0], d0);
  atomicAdd(&denom[col0 + 1], d1);
  atomicAdd(&denom[col0 + 2], d2);
  atomicAdd(&denom[col0 + 3], d3);
  float* np = numer + (size_t)src * Bdim + col0;
  atomicAdd(np + 0, m0);
  atomicAdd(np + 1, m1);
  atomicAdd(np + 2, m2);
  atomicAdd(np + 3, m3);
}

// ---------------------------------------------------------------------------
// Kernel 4 (tiny): out[b] = sigmoid(sum_s numer[s,b]*theta[s,b]/denom[b]+bias)
// ---------------------------------------------------------------------------
__global__ void finalize_kernel(const float* __restrict__ denom,
                                const float* __restrict__ numer,
                                const float* __restrict__ theta,
                                const float* __restrict__ bias,
                                float* __restrict__ out) {
  int b = blockIdx.x * 256 + threadIdx.x;
  float acc = 0.f;
#pragma unroll
  for (int si = 0; si < Sdim; ++si)
    acc += numer[si * Bdim + b] * theta[si * Bdim + b];
  float z = acc / denom[b] + bias[0];
  out[b] = 1.0f / (1.0f + __expf(-z));
}

// ---------------------------------------------------------------------------
// Workspace layout (bytes):
//   catq  : Ndim*Ddim     =  6,291,456   (fp8)
//   xq    : Bdim*Ddim     =  3,145,728   (fp8)
//   con   : Ndim*Bdim*2   = 67,108,864   (bf16)
//   stats : 6*Bdim*4      =     98,304   (s4 | denom | numer)
//   theta : Sdim*Bdim*4   =     65,536
//   total ≈ 76.7 MB
// ---------------------------------------------------------------------------
extern "C" void kernel_launch(void* const* d_in, const int* in_sizes, int n_in,
                              void* d_out, int out_size, void* d_ws,
                              size_t ws_size, hipStream_t stream) {
  const float* batch_x = (const float*)d_in[0];
  const float* cat = (const float*)d_in[1];
  const int* y = (const int*)d_in[2];
  const float* phi = (const float*)d_in[3];
  const float* bias = (const float*)d_in[4];
  float* out = (float*)d_out;

  char* ws = (char*)d_ws;
  unsigned char* catq = (unsigned char*)ws;
  unsigned char* xq = catq + (size_t)Ndim * Ddim;
  unsigned short* con = (unsigned short*)(xq + (size_t)Bdim * Ddim);
  float* stats = (float*)(con + (size_t)Ndim * Bdim);
  float* s4 = stats;
  float* denom = s4 + Bdim;
  float* numer = denom + Bdim;        // Sdim * Bdim
  float* theta = stats + 6 * Bdim;    // Sdim * Bdim

  convert_kernel<<<2048, 256, 0, stream>>>(batch_x, cat, phi, xq, catq, stats,
                                           theta);

  dim3 g2(Ndim / 128, Bdim / 128);
  gemm_bt_kernel<<<g2, 256, 0, stream>>>(catq, xq, con, s4);

  dim3 g3(Bdim / 1024, Ndim / 64);
  expsum_kernel<<<g3, 256, 0, stream>>>(con, s4, y, denom, numer);

  finalize_kernel<<<Bdim / 256, 256, 0, stream>>>(denom, numer, theta, bias,
                                                  out);
}

// Round 9
// 177.058 us; speedup vs baseline: 1.2155x; 1.0229x over previous
//
#include <hip/hip_runtime.h>
#include <hip/hip_bf16.h>
#include <stdint.h>

// Problem constants (from reference): B=4096, D=768, N=8192, S=4
#define Bdim 4096
#define Ddim 768
#define Ndim 8192
#define Sdim 4

typedef __attribute__((ext_vector_type(4))) float floatx4;
typedef __attribute__((ext_vector_type(8))) int int8v;
typedef __attribute__((ext_vector_type(4))) int int4v;

// fp32 -> bf16 round-to-nearest-even, as raw ushort
__device__ inline unsigned short f2bf(float f) {
  unsigned u = __builtin_bit_cast(unsigned, f);
  unsigned r = (u + 0x7fffu + ((u >> 16) & 1u)) >> 16;
  return (unsigned short)r;
}
__device__ inline float bf2f(unsigned short s) {
  return __builtin_bit_cast(float, (unsigned)s << 16);
}

// pack float4 -> 4x fp8 e4m3 (OCP on gfx950), HW RNE
__device__ inline int pack_fp8x4(float4 v) {
  int r = __builtin_amdgcn_cvt_pk_fp8_f32(v.x, v.y, 0, 0);  // low word
  r = __builtin_amdgcn_cvt_pk_fp8_f32(v.z, v.w, r, 1);      // high word
  return r;
}

// async global->LDS, 16B per lane (global_load_lds_dwordx4)
__device__ inline void async_copy16(const void* g, void* l) {
  __builtin_amdgcn_global_load_lds(
      (__attribute__((address_space(1))) void*)(g),
      (__attribute__((address_space(3))) void*)(l),
      16, 0, 0);
}

// ---------------------------------------------------------------------------
// Kernel 1: fp32 -> fp8 e4m3 quantization of batch_x and cat; zero the stats
// region; theta[s,b] = exp(batch_x[b].phi[s]) in fp32 (one wave per b).
// stats = [s4 (B) | denom (B) | numer (S*B)] floats
// ---------------------------------------------------------------------------
__global__ void convert_kernel(const float* __restrict__ x,
                               const float* __restrict__ cat,
                               const float* __restrict__ phi,
                               unsigned char* __restrict__ xq,
                               unsigned char* __restrict__ catq,
                               float* __restrict__ stats,
                               float* __restrict__ theta) {
  int gid = blockIdx.x * blockDim.x + threadIdx.x;
  int stride = gridDim.x * blockDim.x;
  const int nx4 = (Bdim * Ddim) / 4;
  const int nc4 = (Ndim * Ddim) / 4;
  for (int i = gid; i < nx4; i += stride)
    ((int*)xq)[i] = pack_fp8x4(((const float4*)x)[i]);
  for (int i = gid; i < nc4; i += stride)
    ((int*)catq)[i] = pack_fp8x4(((const float4*)cat)[i]);
  if (gid < 6 * Bdim) stats[gid] = 0.0f;

  // theta: one wave per batch row (fp32 — exact path, output-critical)
  int gw = gid >> 6;
  int lane = threadIdx.x & 63;
  if (gw < Bdim) {
    const float* xr = x + (size_t)gw * Ddim;
    float a0 = 0.f, a1 = 0.f, a2 = 0.f, a3 = 0.f;
    for (int d = lane; d < Ddim; d += 64) {
      float xv = xr[d];
      a0 = fmaf(xv, phi[d], a0);
      a1 = fmaf(xv, phi[Ddim + d], a1);
      a2 = fmaf(xv, phi[2 * Ddim + d], a2);
      a3 = fmaf(xv, phi[3 * Ddim + d], a3);
    }
#pragma unroll
    for (int off = 32; off > 0; off >>= 1) {
      a0 += __shfl_down(a0, off);
      a1 += __shfl_down(a1, off);
      a2 += __shfl_down(a2, off);
      a3 += __shfl_down(a3, off);
    }
    if (lane == 0) {
      theta[gw] = __expf(a0);
      theta[Bdim + gw] = __expf(a1);
      theta[2 * Bdim + gw] = __expf(a2);
      theta[3 * Bdim + gw] = __expf(a3);
    }
  }
}

// ---------------------------------------------------------------------------
// Kernel 2: MX-scaled fp8 MFMA GEMM  con[n,b] = sum_k cat[n,k]*x[b,k]
// mfma_scale_f32_16x16x128_f8f6f4 with unit scales (E8M0 0x7F = 2^0):
// mathematically the same fp8 products as R7, 2x MFMA rate, K-loop 12 -> 6
// iterations (m148: 1.64x over non-scaled fp8 on this same structure).
// Lane A/B fragment = 32 consecutive k at k = quad*32+j (K=32 pattern
// k=quad*8+j scaled 4x; = exactly one 32-elem MX scale block).
// LDS: granule-interleaved layout — granule g (16B) of row r lives at slot
// (r>>3)*64 + g*8 + (r&7). Fixes R7's 12-extra-cyc/b64 bank camping
// (32B row stride spanned only 8 banks): fragment ds_read_b128 now hits
// banks (l16&7)*4..+3 uniformly = 8/bank = the b128 structural minimum,
// AND staging sources become 8 rows x 128B contiguous per instruction
// (R7 was 32B units). Dest stays base+lane*16 (global_load_lds constraint;
// padding impossible — m104/m108).
// Natural x-major grid (R4 lesson). Epilogue: bf16 C-write + fused pow4.
// ---------------------------------------------------------------------------
__global__ __launch_bounds__(256) void gemm_bt_kernel(
    const unsigned char* __restrict__ A,    // cat fp8 [Ndim, Ddim]
    const unsigned char* __restrict__ Bm,   // x   fp8 [Bdim, Ddim]
    unsigned short* __restrict__ C,         // con bf16 [Ndim, Bdim]
    float* __restrict__ s4) {               // [Bdim] p4 column sums
  __shared__ unsigned char As[128 * 128];  // 16 KB, granule-interleaved
  __shared__ unsigned char Bs[128 * 128];  // 16 KB

  const int tid = threadIdx.x;
  const int wave = tid >> 6;
  const int lane = tid & 63;
  const int quad = lane >> 4;
  const int l16 = lane & 15;
  const int wm = (wave & 1) * 64;
  const int wn = (wave >> 1) * 64;
  const int m0 = blockIdx.x * 128;
  const int n0 = blockIdx.y * 128;

  floatx4 acc[4][4];
#pragma unroll
  for (int i = 0; i < 4; ++i)
#pragma unroll
    for (int j = 0; j < 4; ++j) acc[i][j] = (floatx4){0.f, 0.f, 0.f, 0.f};

  // staging: 1024 granule-slots per operand per K-iter; slot p holds
  // (row = (p>>6)*8 + (p&7), granule g = (p>>3)&7); 4 slots per thread.
  const unsigned char* a_src[4];
  const unsigned char* b_src[4];
#pragma unroll
  for (int i = 0; i < 4; ++i) {
    int p = tid + 256 * i;
    int row = ((p >> 6) << 3) + (p & 7);
    int colb = ((p >> 3) & 7) * 16;
    a_src[i] = A + (size_t)(m0 + row) * Ddim + colb;
    b_src[i] = Bm + (size_t)(n0 + row) * Ddim + colb;
  }

  for (int k0 = 0; k0 < Ddim; k0 += 128) {
#pragma unroll
    for (int i = 0; i < 4; ++i) {
      async_copy16(a_src[i] + k0, As + (tid + 256 * i) * 16);
      async_copy16(b_src[i] + k0, Bs + (tid + 256 * i) * 16);
    }
    __syncthreads();  // drains vmcnt before barrier

    // fragment: row r, k = quad*32..quad*32+31 = granules 2q,2q+1 ->
    // byte (r>>3)*1024 + quad*256 + (r&7)*16, and +128.
    int8v af[4], bf[4];
#pragma unroll
    for (int mi = 0; mi < 4; ++mi) {
      int r = wm + mi * 16 + l16;
      int base = ((r >> 3) << 10) + quad * 256 + (r & 7) * 16;
      int4v lo = *(const int4v*)(As + base);
      int4v hi = *(const int4v*)(As + base + 128);
      af[mi] = __builtin_shufflevector(lo, hi, 0, 1, 2, 3, 4, 5, 6, 7);
    }
#pragma unroll
    for (int ni = 0; ni < 4; ++ni) {
      int r = wn + ni * 16 + l16;
      int base = ((r >> 3) << 10) + quad * 256 + (r & 7) * 16;
      int4v lo = *(const int4v*)(Bs + base);
      int4v hi = *(const int4v*)(Bs + base + 128);
      bf[ni] = __builtin_shufflevector(lo, hi, 0, 1, 2, 3, 4, 5, 6, 7);
    }
#pragma unroll
    for (int mi = 0; mi < 4; ++mi)
#pragma unroll
      for (int ni = 0; ni < 4; ++ni)
        acc[mi][ni] = __builtin_amdgcn_mfma_scale_f32_16x16x128_f8f6f4(
            af[mi], bf[ni], acc[mi][ni], 0, 0,  // cbsz=0 (fp8), blgp=0 (fp8)
            0, 0x7f7f7f7f,                      // scale A: opsel 0, E8M0 1.0
            0, 0x7f7f7f7f);                     // scale B: opsel 0, E8M0 1.0
    __syncthreads();
  }

  // C/D layout (16x16, shape-determined incl. f8f6f4): col = lane&15,
  // row = quad*4 + reg. Fused pow4 epilogue unchanged (R6/R7-verified).
  float cs4[4] = {0.f, 0.f, 0.f, 0.f};
#pragma unroll
  for (int mi = 0; mi < 4; ++mi)
#pragma unroll
    for (int ni = 0; ni < 4; ++ni) {
      int row = m0 + wm + mi * 16 + quad * 4;
      int col = n0 + wn + ni * 16 + l16;
#pragma unroll
      for (int rr = 0; rr < 4; ++rr) {
        float cv = acc[mi][ni][rr];
        C[(size_t)(row + rr) * Bdim + col] = f2bf(cv);
        float c2 = cv * cv;
        cs4[ni] += c2 * c2;
      }
    }
#pragma unroll
  for (int ni = 0; ni < 4; ++ni) {
    float v = cs4[ni];
    v += __shfl_xor(v, 16);
    v += __shfl_xor(v, 32);
    if (quad == 0) atomicAdd(&s4[n0 + wn + ni * 16 + l16], v);
  }
}

// ---------------------------------------------------------------------------
// Kernel 3: denom[b] += sum exp(con/norm4); numer[s,b] += y-masked sum.
// norm4 >= max|con| so logits are in [-1,1]: no max-subtraction needed.
// Thread owns 4 consecutive columns (ushort4 loads, 512B/wave coalesced).
// Stream ordering (not fences) is the cross-kernel coherence path (R3/R5).
// ---------------------------------------------------------------------------
__global__ void expsum_kernel(const unsigned short* __restrict__ con,
                              const float* __restrict__ s4,
                              const int* __restrict__ y,
                              float* __restrict__ denom,
                              float* __restrict__ numer) {
  int col0 = blockIdx.x * 1024 + threadIdx.x * 4;
  int n0 = blockIdx.y * 64;
  int src = n0 / (Ndim / Sdim);  // 64-row chunk is always within one source

  float4 s = *(const float4*)(s4 + col0);
  float inv0 = 1.0f / fmaxf(sqrtf(sqrtf(s.x)), 1e-12f);
  float inv1 = 1.0f / fmaxf(sqrtf(sqrtf(s.y)), 1e-12f);
  float inv2 = 1.0f / fmaxf(sqrtf(sqrtf(s.z)), 1e-12f);
  float inv3 = 1.0f / fmaxf(sqrtf(sqrtf(s.w)), 1e-12f);

  const unsigned short* p = con + (size_t)n0 * Bdim + col0;
  float d0 = 0.f, d1 = 0.f, d2 = 0.f, d3 = 0.f;
  float m0 = 0.f, m1 = 0.f, m2 = 0.f, m3 = 0.f;
#pragma unroll 8
  for (int i = 0; i < 64; ++i) {
    ushort4 v = *(const ushort4*)(p + (size_t)i * Bdim);
    float yv = (float)y[n0 + i];  // wave-uniform, cached
    float e0 = __expf(bf2f(v.x) * inv0);
    float e1 = __expf(bf2f(v.y) * inv1);
    float e2 = __expf(bf2f(v.z) * inv2);
    float e3 = __expf(bf2f(v.w) * inv3);
    d0 += e0; d1 += e1; d2 += e2; d3 += e3;
    m0 += e0 * yv; m1 += e1 * yv; m2 += e2 * yv; m3 += e3 * yv;
  }
  atomicAdd(&denom[col0 + 0], d0);
  atomicAdd(&denom[col0 + 1], d1);
  atomicAdd(&denom[col0 + 2], d2);
  atomicAdd(&denom[col0 + 3], d3);
  float* np = numer + (size_t)src * Bdim + col0;
  atomicAdd(np + 0, m0);
  atomicAdd(np + 1, m1);
  atomicAdd(np + 2, m2);
  atomicAdd(np + 3, m3);
}

// ---------------------------------------------------------------------------
// Kernel 4 (tiny): out[b] = sigmoid(sum_s numer[s,b]*theta[s,b]/denom[b]+bias)
// ---------------------------------------------------------------------------
__global__ void finalize_kernel(const float* __restrict__ denom,
                                const float* __restrict__ numer,
                                const float* __restrict__ theta,
                                const float* __restrict__ bias,
                                float* __restrict__ out) {
  int b = blockIdx.x * 256 + threadIdx.x;
  float acc = 0.f;
#pragma unroll
  for (int si = 0; si < Sdim; ++si)
    acc += numer[si * Bdim + b] * theta[si * Bdim + b];
  float z = acc / denom[b] + bias[0];
  out[b] = 1.0f / (1.0f + __expf(-z));
}

// ---------------------------------------------------------------------------
// Workspace layout (bytes):
//   catq  : Ndim*Ddim     =  6,291,456   (fp8)
//   xq    : Bdim*Ddim     =  3,145,728   (fp8)
//   con   : Ndim*Bdim*2   = 67,108,864   (bf16)
//   stats : 6*Bdim*4      =     98,304   (s4 | denom | numer)
//   theta : Sdim*Bdim*4   =     65,536
//   total ≈ 76.7 MB
// ---------------------------------------------------------------------------
extern "C" void kernel_launch(void* const* d_in, const int* in_sizes, int n_in,
                              void* d_out, int out_size, void* d_ws,
                              size_t ws_size, hipStream_t stream) {
  const float* batch_x = (const float*)d_in[0];
  const float* cat = (const float*)d_in[1];
  const int* y = (const int*)d_in[2];
  const float* phi = (const float*)d_in[3];
  const float* bias = (const float*)d_in[4];
  float* out = (float*)d_out;

  char* ws = (char*)d_ws;
  unsigned char* catq = (unsigned char*)ws;
  unsigned char* xq = catq + (size_t)Ndim * Ddim;
  unsigned short* con = (unsigned short*)(xq + (size_t)Bdim * Ddim);
  float* stats = (float*)(con + (size_t)Ndim * Bdim);
  float* s4 = stats;
  float* denom = s4 + Bdim;
  float* numer = denom + Bdim;        // Sdim * Bdim
  float* theta = stats + 6 * Bdim;    // Sdim * Bdim

  convert_kernel<<<2048, 256, 0, stream>>>(batch_x, cat, phi, xq, catq, stats,
                                           theta);

  dim3 g2(Ndim / 128, Bdim / 128);
  gemm_bt_kernel<<<g2, 256, 0, stream>>>(catq, xq, con, s4);

  dim3 g3(Bdim / 1024, Ndim / 64);
  expsum_kernel<<<g3, 256, 0, stream>>>(con, s4, y, denom, numer);

  finalize_kernel<<<Bdim / 256, 256, 0, stream>>>(denom, numer, theta, bias,
                                                  out);
}